// Round 12
// baseline (474.259 us; speedup 1.0000x reference)
//
#include <hip/hip_runtime.h>

#define N_USERS 100000
#define N_ITEMS 50000
#define N_NODES 150000
#define DIM 32
#define N_EDGES 8000000
#define B_OUT 65536

#define NB 1024                      // row buckets
#define RPB 147                      // rows per bucket (1024*147 >= 150000)
#define CH 16384                     // edges per chunk (payload fits LDS)
#define N_PBLK ((N_EDGES + CH - 1) / CH)   // 489
#define PART_T 1024
#define EPT (CH / PART_T)            // 16 edges per thread
#define MS_T 512
#define T 256
#define NRED 8
#define RS_LD (NB + 1)               // runstart leading dim: [chunk][NB+1]
#define NPANEL 3
#define NBIN (RPB * NPANEL)          // 441 (row_local, panel) bins

__device__ __forceinline__ unsigned short f2bf(float f) {
    unsigned b = __float_as_uint(f);
    return (unsigned short)((b + 0x7FFFu + ((b >> 16) & 1u)) >> 16);   // RNE
}
__device__ __forceinline__ float bflo(unsigned u) {
    return __uint_as_float(u << 16);
}
__device__ __forceinline__ float bfhi(unsigned u) {
    return __uint_as_float(u & 0xFFFF0000u);
}
__device__ __forceinline__ int panel_of(int col) {
    return (col >= 100000) ? 2 : ((col >= 50000) ? 1 : 0);
}

// ---------------------------------------------------------------------------
// init: x_a(bf16) = concat(user_emb, item_emb).
// ---------------------------------------------------------------------------
__global__ void init_kernel(const float* __restrict__ user_emb,
                            const float* __restrict__ item_emb,
                            unsigned short* __restrict__ x_a) {
    int i = blockIdx.x * blockDim.x + threadIdx.x;   // float4 index
    const int total = N_NODES * DIM / 4;
    if (i >= total) return;
    const int user_f4 = N_USERS * DIM / 4;
    float4 v;
    if (i < user_f4) v = ((const float4*)user_emb)[i];
    else             v = ((const float4*)item_emb)[i - user_f4];
    ushort4 h;
    h.x = f2bf(v.x); h.y = f2bf(v.y); h.z = f2bf(v.z); h.w = f2bf(v.w);
    ((ushort4*)x_a)[i] = h;
}

// ---------------------------------------------------------------------------
// Partition (proven R8): LDS histogram -> shuffle scan -> rank into LDS
// payload -> coalesced stream-out. Payload: int2{ (row_local<<18)|col, val }.
// ---------------------------------------------------------------------------
__global__ void __launch_bounds__(PART_T)
part_kernel(const int* __restrict__ rows,
            const int* __restrict__ cols,
            const float* __restrict__ vals,
            int* __restrict__ runstart,
            int2* __restrict__ bucket_ev) {
    __shared__ int2 buf[CH];         // 128 KB staged payload
    __shared__ int hist[NB];         // 4 KB
    __shared__ int wsum[16];
    const int tid   = threadIdx.x;
    const int chunk = blockIdx.x;
    const int e0    = chunk * CH;
    const int ecnt  = (N_EDGES - e0 < CH) ? (N_EDGES - e0) : CH;
    const int lane  = tid & 63, wid = tid >> 6;

    hist[tid] = 0;
    __syncthreads();

    int myrow[EPT];
    #pragma unroll
    for (int j = 0; j < EPT; ++j) {
        int idx = j * PART_T + tid;
        int r = (idx < ecnt) ? rows[e0 + idx] : -1;
        myrow[j] = r;
        if (r >= 0) atomicAdd(&hist[(unsigned)r / RPB], 1);
    }
    __syncthreads();

    int v = hist[tid];
    int inc = v;
    #pragma unroll
    for (int off = 1; off < 64; off <<= 1) {
        int t = __shfl_up(inc, off, 64);
        if (lane >= off) inc += t;
    }
    if (lane == 63) wsum[wid] = inc;
    __syncthreads();
    if (wid == 0) {
        int s = (lane < 16) ? wsum[lane] : 0;
        #pragma unroll
        for (int off = 1; off < 16; off <<= 1) {
            int t = __shfl_up(s, off, 64);
            if (lane >= off) s += t;
        }
        if (lane < 16) wsum[lane] = s;
    }
    __syncthreads();
    int base = (wid > 0) ? wsum[wid - 1] : 0;
    int incl = base + inc;
    int excl = incl - v;
    runstart[(size_t)chunk * RS_LD + tid] = e0 + excl;
    if (tid == NB - 1) runstart[(size_t)chunk * RS_LD + NB] = e0 + incl;
    hist[tid] = excl;
    __syncthreads();

    #pragma unroll
    for (int j = 0; j < EPT; ++j) {
        int r = myrow[j];
        if (r < 0) continue;
        int idx = j * PART_T + tid;
        unsigned b = (unsigned)r / RPB;
        int k = atomicAdd(&hist[b], 1);
        int2 ev;
        ev.x = (int)(((unsigned)(r - (int)b * RPB) << 18) | (unsigned)cols[e0 + idx]);
        ev.y = __float_as_int(vals[e0 + idx]);
        buf[k] = ev;
    }
    __syncthreads();

    const int n4 = ecnt >> 1;
    const int4* b4 = (const int4*)buf;
    int4* g4 = (int4*)(bucket_ev + e0);
    for (int i = tid; i < n4; i += PART_T) g4[i] = b4[i];
}

// ---------------------------------------------------------------------------
// Bucket totals + scan -> bcsr.
// ---------------------------------------------------------------------------
__global__ void btot_kernel(const int* __restrict__ runstart, int* __restrict__ partial) {
    const int b = threadIdx.x;
    const int g = blockIdx.x;
    int c = 0;
    for (int ch = g; ch < N_PBLK; ch += NRED)
        c += runstart[(size_t)ch * RS_LD + b + 1] - runstart[(size_t)ch * RS_LD + b];
    partial[g * NB + b] = c;
}

__global__ void bscan_kernel(const int* __restrict__ partial,
                             int* __restrict__ bcsr,
                             int* __restrict__ row_ptr) {
    __shared__ int wsum[16];
    const int tid = threadIdx.x;
    const int lane = tid & 63, wid = tid >> 6;
    int v = 0;
    #pragma unroll
    for (int g = 0; g < NRED; ++g) v += partial[g * NB + tid];
    int inc = v;
    #pragma unroll
    for (int off = 1; off < 64; off <<= 1) {
        int t = __shfl_up(inc, off, 64);
        if (lane >= off) inc += t;
    }
    if (lane == 63) wsum[wid] = inc;
    __syncthreads();
    if (wid == 0) {
        int s = (lane < 16) ? wsum[lane] : 0;
        #pragma unroll
        for (int off = 1; off < 16; off <<= 1) {
            int t = __shfl_up(s, off, 64);
            if (lane >= off) s += t;
        }
        if (lane < 16) wsum[lane] = s;
    }
    __syncthreads();
    int base = (wid > 0) ? wsum[wid - 1] : 0;
    bcsr[tid] = base + inc - v;          // exclusive
    if (tid == 0) row_ptr[N_NODES] = N_EDGES;
}

// ---------------------------------------------------------------------------
// Mini-scatter: one block per bucket, 16-lane groups. Bins are
// (row_local, col-panel) -> within each row the CSR is panel-sorted,
// giving the SpMM a phase-aligned (L2-resident) gather working set.
// ---------------------------------------------------------------------------
__global__ void __launch_bounds__(MS_T)
mini_scatter_kernel(const int* __restrict__ runstart,
                    const int2* __restrict__ bucket_ev,
                    const int* __restrict__ bcsr,
                    int* __restrict__ row_ptr,
                    int2* __restrict__ csr_ev) {
    __shared__ int rs0[N_PBLK];
    __shared__ int rs1[N_PBLK];
    __shared__ int cnt2[NBIN];
    __shared__ int cur2[NBIN];
    __shared__ int wsum[MS_T / 64];
    const int b   = blockIdx.x;
    const int tid = threadIdx.x;
    const int lane = tid & 63, wid = tid >> 6;

    for (int i = tid; i < N_PBLK; i += MS_T) {
        rs0[i] = runstart[(size_t)i * RS_LD + b];
        rs1[i] = runstart[(size_t)i * RS_LD + b + 1];
    }
    if (tid < NBIN) cnt2[tid] = 0;
    __syncthreads();

    const int grp = tid >> 4, ln = tid & 15;     // 16-lane groups
    for (int c = grp; c < N_PBLK; c += (MS_T / 16))
        for (int i = rs0[c] + ln; i < rs1[c]; i += 16) {
            unsigned key = (unsigned)bucket_ev[i].x;
            int rl  = (int)(key >> 18);
            int col = (int)(key & 0x3FFFFu);
            atomicAdd(&cnt2[rl * NPANEL + panel_of(col)], 1);
        }
    __syncthreads();

    int v = (tid < NBIN) ? cnt2[tid] : 0;
    int inc = v;
    #pragma unroll
    for (int off = 1; off < 64; off <<= 1) {
        int t = __shfl_up(inc, off, 64);
        if (lane >= off) inc += t;
    }
    if (lane == 63) wsum[wid] = inc;
    __syncthreads();
    if (wid == 0) {
        int s = (lane < MS_T / 64) ? wsum[lane] : 0;
        #pragma unroll
        for (int off = 1; off < MS_T / 64; off <<= 1) {
            int t = __shfl_up(s, off, 64);
            if (lane >= off) s += t;
        }
        if (lane < MS_T / 64) wsum[lane] = s;
    }
    __syncthreads();
    const int cb = bcsr[b];
    if (tid < NBIN) {
        int base = (wid > 0) ? wsum[wid - 1] : 0;
        int excl = cb + base + inc - v;
        cur2[tid] = excl;
        if (tid % NPANEL == 0) {
            int r = b * RPB + tid / NPANEL;
            if (r < N_NODES) row_ptr[r] = excl;
        }
    }
    __syncthreads();

    for (int c = grp; c < N_PBLK; c += (MS_T / 16))
        for (int i = rs0[c] + ln; i < rs1[c]; i += 16) {
            int2 ev = bucket_ev[i];
            unsigned key = (unsigned)ev.x;
            int rl  = (int)(key >> 18);
            int col = (int)(key & 0x3FFFFu);
            int pos = atomicAdd(&cur2[rl * NPANEL + panel_of(col)], 1);
            int2 o; o.x = col; o.y = ev.y;
            csr_ev[pos] = o;
        }
}

// ---------------------------------------------------------------------------
// CSR SpMM, 16B-granular bf16 gather (proven R11), bf16 out, no emb_sum.
// Half-wave per row; lane = (edge-slot j = 0..7, seg = 0..3).
// ---------------------------------------------------------------------------
__global__ void spmm_kernel(const int* __restrict__ row_ptr,
                            const long long* __restrict__ csr,
                            const unsigned short* __restrict__ xin,
                            unsigned short* __restrict__ xout) {
    int tid = blockIdx.x * blockDim.x + threadIdx.x;
    int row = tid >> 5;
    if (row >= N_NODES) return;
    const int ll  = tid & 31;
    const int j   = ll >> 2;     // edge slot 0..7
    const int seg = ll & 3;      // 8-dim segment 0..3
    const int s = row_ptr[row];
    const int e = row_ptr[row + 1];

    float acc[8];
    #pragma unroll
    for (int k = 0; k < 8; ++k) acc[k] = 0.f;

    for (int i = s; i < e; i += 16) {
        int ea = i + j;
        int eb = i + 8 + j;
        long long pa = (ea < e) ? csr[ea] : 0LL;
        long long pb = (eb < e) ? csr[eb] : 0LL;
        const uint4* qa = (const uint4*)(xin + ((unsigned)pa) * DIM) + seg;
        const uint4* qb = (const uint4*)(xin + ((unsigned)pb) * DIM) + seg;
        uint4 va = *qa;
        uint4 vb = *qb;
        float wa = __int_as_float((int)(pa >> 32));
        float wb = __int_as_float((int)(pb >> 32));
        acc[0] += wa * bflo(va.x); acc[1] += wa * bfhi(va.x);
        acc[2] += wa * bflo(va.y); acc[3] += wa * bfhi(va.y);
        acc[4] += wa * bflo(va.z); acc[5] += wa * bfhi(va.z);
        acc[6] += wa * bflo(va.w); acc[7] += wa * bfhi(va.w);
        acc[0] += wb * bflo(vb.x); acc[1] += wb * bfhi(vb.x);
        acc[2] += wb * bflo(vb.y); acc[3] += wb * bfhi(vb.y);
        acc[4] += wb * bflo(vb.z); acc[5] += wb * bfhi(vb.z);
        acc[6] += wb * bflo(vb.w); acc[7] += wb * bfhi(vb.w);
    }

    #pragma unroll
    for (int m = 4; m <= 16; m <<= 1) {
        #pragma unroll
        for (int k = 0; k < 8; ++k) acc[k] += __shfl_xor(acc[k], m, 64);
    }

    if (j == 0) {
        int o = row * DIM + seg * 8;
        uint4 h;
        h.x = (unsigned)f2bf(acc[0]) | ((unsigned)f2bf(acc[1]) << 16);
        h.y = (unsigned)f2bf(acc[2]) | ((unsigned)f2bf(acc[3]) << 16);
        h.z = (unsigned)f2bf(acc[4]) | ((unsigned)f2bf(acc[5]) << 16);
        h.w = (unsigned)f2bf(acc[6]) | ((unsigned)f2bf(acc[7]) << 16);
        *(uint4*)(xout + o) = h;
    }
}

// ---------------------------------------------------------------------------
// Readout: light = (e + x1 + x2 + x3)/4 reconstructed per accessed node.
// ---------------------------------------------------------------------------
__device__ __forceinline__ void add_bf16_row(float* s, const unsigned short* x, size_t node) {
    const uint4* p = (const uint4*)(x + node * DIM);
    #pragma unroll
    for (int k = 0; k < 4; ++k) {
        uint4 t = p[k];
        s[k * 8 + 0] += bflo(t.x); s[k * 8 + 1] += bfhi(t.x);
        s[k * 8 + 2] += bflo(t.y); s[k * 8 + 3] += bfhi(t.y);
        s[k * 8 + 4] += bflo(t.z); s[k * 8 + 5] += bfhi(t.z);
        s[k * 8 + 6] += bflo(t.w); s[k * 8 + 7] += bfhi(t.w);
    }
}

__global__ void final_kernel(const int* __restrict__ users,
                             const int* __restrict__ items,
                             const float* __restrict__ user_emb,
                             const float* __restrict__ item_emb,
                             const unsigned short* __restrict__ x1,
                             const unsigned short* __restrict__ x2,
                             const unsigned short* __restrict__ x3,
                             const float* __restrict__ means,
                             const float* __restrict__ stds,
                             float* __restrict__ out) {
    int b = blockIdx.x * blockDim.x + threadIdx.x;
    if (b >= B_OUT) return;
    int u  = users[b];
    int itm = items[b];
    size_t un = (size_t)u;
    size_t in = (size_t)(N_USERS + itm);

    float su[DIM], si[DIM];
    const float4* eu = (const float4*)(user_emb + un * DIM);
    const float4* ei = (const float4*)(item_emb + (size_t)itm * DIM);
    #pragma unroll
    for (int k = 0; k < 8; ++k) {
        float4 a = eu[k];
        su[k * 4 + 0] = a.x; su[k * 4 + 1] = a.y; su[k * 4 + 2] = a.z; su[k * 4 + 3] = a.w;
        float4 c = ei[k];
        si[k * 4 + 0] = c.x; si[k * 4 + 1] = c.y; si[k * 4 + 2] = c.z; si[k * 4 + 3] = c.w;
    }
    add_bf16_row(su, x1, un); add_bf16_row(su, x2, un); add_bf16_row(su, x3, un);
    add_bf16_row(si, x1, in); add_bf16_row(si, x2, in); add_bf16_row(si, x3, in);

    float gamma = 0.f;
    #pragma unroll
    for (int d = 0; d < DIM; ++d) gamma += su[d] * si[d];
    gamma *= 0.0625f;   // (1/4)*(1/4)
    out[b] = gamma * stds[u] + means[u];
}

extern "C" void kernel_launch(void* const* d_in, const int* in_sizes, int n_in,
                              void* d_out, int out_size, void* d_ws, size_t ws_size,
                              hipStream_t stream) {
    const int*   users    = (const int*)d_in[0];
    const int*   items    = (const int*)d_in[1];
    const int*   rows     = (const int*)d_in[2];
    const int*   cols     = (const int*)d_in[3];
    const float* vals     = (const float*)d_in[4];
    const float* user_emb = (const float*)d_in[5];
    const float* item_emb = (const float*)d_in[6];
    const float* means    = (const float*)d_in[7];
    const float* stds     = (const float*)d_in[8];
    float* out = (float*)d_out;

    char* w = (char*)d_ws;
    size_t off = 0;
    auto alloc = [&](size_t bytes) -> void* {
        void* p = w + off;
        off = (off + bytes + 255) & ~(size_t)255;
        return p;
    };
    // Region A: bucket_ev (live: part -> mini_scatter) aliases
    //           {x_a, x_b, x_c, x_d} (live: init -> end).
    size_t regionA = ((size_t)N_PBLK * CH * sizeof(int2) + 255) & ~(size_t)255;  // 64.1 MB
    char* a0 = (char*)alloc(regionA);
    int2* bucket_ev = (int2*)a0;
    size_t aoff = 0;
    auto allocA = [&](size_t bytes) -> void* {
        void* p = a0 + aoff;
        aoff = (aoff + bytes + 255) & ~(size_t)255;
        return p;
    };
    unsigned short* x_a = (unsigned short*)allocA((size_t)N_NODES * DIM * 2);  // 9.6 MB
    unsigned short* x_b = (unsigned short*)allocA((size_t)N_NODES * DIM * 2);  // 9.6 MB
    unsigned short* x_c = (unsigned short*)allocA((size_t)N_NODES * DIM * 2);  // 9.6 MB
    unsigned short* x_d = (unsigned short*)allocA((size_t)N_NODES * DIM * 2);  // 9.6 MB (38.4 <= 64.1)

    int*  runstart = (int*) alloc((size_t)N_PBLK * RS_LD * sizeof(int));       // 2.0 MB
    int*  partial  = (int*) alloc((size_t)NRED * NB * sizeof(int));
    int*  row_ptr  = (int*) alloc((size_t)(N_NODES + 1) * sizeof(int));
    int*  bcsr     = (int*) alloc((size_t)NB * sizeof(int));
    int2* csr_ev   = (int2*)alloc((size_t)N_EDGES * sizeof(int2));              // 64 MB
    const long long* csr = (const long long*)csr_ev;
    (void)ws_size;

    const int g_init  = (N_NODES * DIM / 4 + T - 1) / T;
    const int g_spmm  = (N_NODES * DIM + T - 1) / T;     // 18750
    const int g_final = (B_OUT + T - 1) / T;

    // --- CSR build (panel-sorted within rows) ---
    part_kernel<<<N_PBLK, PART_T, 0, stream>>>(rows, cols, vals, runstart, bucket_ev);
    btot_kernel<<<NRED, NB, 0, stream>>>(runstart, partial);
    bscan_kernel<<<1, NB, 0, stream>>>(partial, bcsr, row_ptr);
    mini_scatter_kernel<<<NB, MS_T, 0, stream>>>(runstart, bucket_ev, bcsr, row_ptr, csr_ev);

    // --- dense pipeline (bucket_ev dead from here; region reused) ---
    init_kernel<<<g_init, T, 0, stream>>>(user_emb, item_emb, x_a);
    spmm_kernel<<<g_spmm, T, 0, stream>>>(row_ptr, csr, x_a, x_b);
    spmm_kernel<<<g_spmm, T, 0, stream>>>(row_ptr, csr, x_b, x_c);
    spmm_kernel<<<g_spmm, T, 0, stream>>>(row_ptr, csr, x_c, x_d);

    final_kernel<<<g_final, T, 0, stream>>>(users, items, user_emb, item_emb,
                                            x_b, x_c, x_d, means, stds, out);
}

// Round 13
// 430.502 us; speedup vs baseline: 1.1016x; 1.1016x over previous
//
#include <hip/hip_runtime.h>

#define N_USERS 100000
#define N_ITEMS 50000
#define N_NODES 150000
#define DIM 32
#define N_EDGES 8000000
#define B_OUT 65536

#define NB 1024                      // row buckets
#define RPB 147                      // rows per bucket (1024*147 >= 150000)
#define CH 16384                     // edges per chunk (payload fits LDS)
#define N_PBLK ((N_EDGES + CH - 1) / CH)   // 489
#define PART_T 1024
#define EPT (CH / PART_T)            // 16 edges per thread
#define MS_T 512
#define T 256
#define NRED 8
#define RS_LD (NB + 1)               // runstart leading dim: [chunk][NB+1]
#define NPANEL 3
#define NBIN (RPB * NPANEL)          // 441 (row_local, panel) bins
#define BUFE 8448                    // LDS staging capacity (mean 7840, +7 sigma)

__device__ __forceinline__ unsigned short f2bf(float f) {
    unsigned b = __float_as_uint(f);
    return (unsigned short)((b + 0x7FFFu + ((b >> 16) & 1u)) >> 16);   // RNE
}
__device__ __forceinline__ float bflo(unsigned u) {
    return __uint_as_float(u << 16);
}
__device__ __forceinline__ float bfhi(unsigned u) {
    return __uint_as_float(u & 0xFFFF0000u);
}
__device__ __forceinline__ int panel_of(int col) {
    return (col >= 100000) ? 2 : ((col >= 50000) ? 1 : 0);
}

// ---------------------------------------------------------------------------
// init: x_a(bf16) = concat(user_emb, item_emb).
// ---------------------------------------------------------------------------
__global__ void init_kernel(const float* __restrict__ user_emb,
                            const float* __restrict__ item_emb,
                            unsigned short* __restrict__ x_a) {
    int i = blockIdx.x * blockDim.x + threadIdx.x;   // float4 index
    const int total = N_NODES * DIM / 4;
    if (i >= total) return;
    const int user_f4 = N_USERS * DIM / 4;
    float4 v;
    if (i < user_f4) v = ((const float4*)user_emb)[i];
    else             v = ((const float4*)item_emb)[i - user_f4];
    ushort4 h;
    h.x = f2bf(v.x); h.y = f2bf(v.y); h.z = f2bf(v.z); h.w = f2bf(v.w);
    ((ushort4*)x_a)[i] = h;
}

// ---------------------------------------------------------------------------
// Partition (proven R8): LDS histogram -> shuffle scan -> rank into LDS
// payload -> coalesced stream-out. Payload: int2{ (row_local<<18)|col, val }.
// ---------------------------------------------------------------------------
__global__ void __launch_bounds__(PART_T)
part_kernel(const int* __restrict__ rows,
            const int* __restrict__ cols,
            const float* __restrict__ vals,
            int* __restrict__ runstart,
            int2* __restrict__ bucket_ev) {
    __shared__ int2 buf[CH];         // 128 KB staged payload
    __shared__ int hist[NB];         // 4 KB
    __shared__ int wsum[16];
    const int tid   = threadIdx.x;
    const int chunk = blockIdx.x;
    const int e0    = chunk * CH;
    const int ecnt  = (N_EDGES - e0 < CH) ? (N_EDGES - e0) : CH;
    const int lane  = tid & 63, wid = tid >> 6;

    hist[tid] = 0;
    __syncthreads();

    int myrow[EPT];
    #pragma unroll
    for (int j = 0; j < EPT; ++j) {
        int idx = j * PART_T + tid;
        int r = (idx < ecnt) ? rows[e0 + idx] : -1;
        myrow[j] = r;
        if (r >= 0) atomicAdd(&hist[(unsigned)r / RPB], 1);
    }
    __syncthreads();

    int v = hist[tid];
    int inc = v;
    #pragma unroll
    for (int off = 1; off < 64; off <<= 1) {
        int t = __shfl_up(inc, off, 64);
        if (lane >= off) inc += t;
    }
    if (lane == 63) wsum[wid] = inc;
    __syncthreads();
    if (wid == 0) {
        int s = (lane < 16) ? wsum[lane] : 0;
        #pragma unroll
        for (int off = 1; off < 16; off <<= 1) {
            int t = __shfl_up(s, off, 64);
            if (lane >= off) s += t;
        }
        if (lane < 16) wsum[lane] = s;
    }
    __syncthreads();
    int base = (wid > 0) ? wsum[wid - 1] : 0;
    int incl = base + inc;
    int excl = incl - v;
    runstart[(size_t)chunk * RS_LD + tid] = e0 + excl;
    if (tid == NB - 1) runstart[(size_t)chunk * RS_LD + NB] = e0 + incl;
    hist[tid] = excl;
    __syncthreads();

    #pragma unroll
    for (int j = 0; j < EPT; ++j) {
        int r = myrow[j];
        if (r < 0) continue;
        int idx = j * PART_T + tid;
        unsigned b = (unsigned)r / RPB;
        int k = atomicAdd(&hist[b], 1);
        int2 ev;
        ev.x = (int)(((unsigned)(r - (int)b * RPB) << 18) | (unsigned)cols[e0 + idx]);
        ev.y = __float_as_int(vals[e0 + idx]);
        buf[k] = ev;
    }
    __syncthreads();

    const int n4 = ecnt >> 1;
    const int4* b4 = (const int4*)buf;
    int4* g4 = (int4*)(bucket_ev + e0);
    for (int i = tid; i < n4; i += PART_T) g4[i] = b4[i];
}

// ---------------------------------------------------------------------------
// Bucket totals + scan -> bcsr.
// ---------------------------------------------------------------------------
__global__ void btot_kernel(const int* __restrict__ runstart, int* __restrict__ partial) {
    const int b = threadIdx.x;
    const int g = blockIdx.x;
    int c = 0;
    for (int ch = g; ch < N_PBLK; ch += NRED)
        c += runstart[(size_t)ch * RS_LD + b + 1] - runstart[(size_t)ch * RS_LD + b];
    partial[g * NB + b] = c;
}

__global__ void bscan_kernel(const int* __restrict__ partial,
                             int* __restrict__ bcsr,
                             int* __restrict__ row_ptr) {
    __shared__ int wsum[16];
    const int tid = threadIdx.x;
    const int lane = tid & 63, wid = tid >> 6;
    int v = 0;
    #pragma unroll
    for (int g = 0; g < NRED; ++g) v += partial[g * NB + tid];
    int inc = v;
    #pragma unroll
    for (int off = 1; off < 64; off <<= 1) {
        int t = __shfl_up(inc, off, 64);
        if (lane >= off) inc += t;
    }
    if (lane == 63) wsum[wid] = inc;
    __syncthreads();
    if (wid == 0) {
        int s = (lane < 16) ? wsum[lane] : 0;
        #pragma unroll
        for (int off = 1; off < 16; off <<= 1) {
            int t = __shfl_up(s, off, 64);
            if (lane >= off) s += t;
        }
        if (lane < 16) wsum[lane] = s;
    }
    __syncthreads();
    int base = (wid > 0) ? wsum[wid - 1] : 0;
    bcsr[tid] = base + inc - v;          // exclusive
    if (tid == 0) row_ptr[N_NODES] = N_EDGES;
}

// ---------------------------------------------------------------------------
// Mini-scatter v2: one block per bucket. (row_local, panel) bins -> LDS
// cursors; scatter lands in an LDS staging buffer (bucket span ~63KB),
// then streams out SEQUENTIALLY to csr_ev. Random writes never hit L2.
// Fallback to direct scatter if bucket exceeds BUFE (never, statistically).
// ---------------------------------------------------------------------------
__global__ void __launch_bounds__(MS_T)
mini_scatter_kernel(const int* __restrict__ runstart,
                    const int2* __restrict__ bucket_ev,
                    const int* __restrict__ bcsr,
                    int* __restrict__ row_ptr,
                    int2* __restrict__ csr_ev) {
    __shared__ int2 sbuf[BUFE];      // 66 KB staging
    __shared__ int rs0[N_PBLK];
    __shared__ int rs1[N_PBLK];
    __shared__ int cnt2[NBIN];
    __shared__ int cur2[NBIN];
    __shared__ int wsum[MS_T / 64];
    __shared__ int stot;
    const int b   = blockIdx.x;
    const int tid = threadIdx.x;
    const int lane = tid & 63, wid = tid >> 6;

    for (int i = tid; i < N_PBLK; i += MS_T) {
        rs0[i] = runstart[(size_t)i * RS_LD + b];
        rs1[i] = runstart[(size_t)i * RS_LD + b + 1];
    }
    if (tid < NBIN) cnt2[tid] = 0;
    __syncthreads();

    const int grp = tid >> 4, ln = tid & 15;     // 16-lane groups
    for (int c = grp; c < N_PBLK; c += (MS_T / 16))
        for (int i = rs0[c] + ln; i < rs1[c]; i += 16) {
            unsigned key = (unsigned)bucket_ev[i].x;
            int rl  = (int)(key >> 18);
            int col = (int)(key & 0x3FFFFu);
            atomicAdd(&cnt2[rl * NPANEL + panel_of(col)], 1);
        }
    __syncthreads();

    int v = (tid < NBIN) ? cnt2[tid] : 0;
    int inc = v;
    #pragma unroll
    for (int off = 1; off < 64; off <<= 1) {
        int t = __shfl_up(inc, off, 64);
        if (lane >= off) inc += t;
    }
    if (lane == 63) wsum[wid] = inc;
    __syncthreads();
    if (wid == 0) {
        int s = (lane < MS_T / 64) ? wsum[lane] : 0;
        #pragma unroll
        for (int off = 1; off < MS_T / 64; off <<= 1) {
            int t = __shfl_up(s, off, 64);
            if (lane >= off) s += t;
        }
        if (lane < MS_T / 64) wsum[lane] = s;
    }
    __syncthreads();
    const int cb = bcsr[b];
    int base = (wid > 0) ? wsum[wid - 1] : 0;
    if (tid == NBIN - 1) stot = base + inc;      // bucket total
    if (tid < NBIN) {
        int excl = base + inc - v;               // bucket-local exclusive
        cur2[tid] = excl;
        if (tid % NPANEL == 0) {
            int r = b * RPB + tid / NPANEL;
            if (r < N_NODES) row_ptr[r] = cb + excl;
        }
    }
    __syncthreads();
    const int cnt = stot;

    if (cnt <= BUFE) {
        // scatter into LDS staging (bucket-local offsets)
        for (int c = grp; c < N_PBLK; c += (MS_T / 16))
            for (int i = rs0[c] + ln; i < rs1[c]; i += 16) {
                int2 ev = bucket_ev[i];
                unsigned key = (unsigned)ev.x;
                int rl  = (int)(key >> 18);
                int col = (int)(key & 0x3FFFFu);
                int pos = atomicAdd(&cur2[rl * NPANEL + panel_of(col)], 1);
                int2 o; o.x = col; o.y = ev.y;
                sbuf[pos] = o;
            }
        __syncthreads();
        // sequential stream-out
        int2* g = csr_ev + cb;
        for (int i = tid; i < cnt; i += MS_T) g[i] = sbuf[i];
    } else {
        // statistical never-path: direct global scatter
        for (int c = grp; c < N_PBLK; c += (MS_T / 16))
            for (int i = rs0[c] + ln; i < rs1[c]; i += 16) {
                int2 ev = bucket_ev[i];
                unsigned key = (unsigned)ev.x;
                int rl  = (int)(key >> 18);
                int col = (int)(key & 0x3FFFFu);
                int pos = atomicAdd(&cur2[rl * NPANEL + panel_of(col)], 1);
                int2 o; o.x = col; o.y = ev.y;
                csr_ev[cb + pos] = o;
            }
    }
}

// ---------------------------------------------------------------------------
// CSR SpMM, 16B-granular bf16 gather (proven R11), bf16 out.
// Half-wave per row; lane = (edge-slot j = 0..7, seg = 0..3).
// ---------------------------------------------------------------------------
__global__ void spmm_kernel(const int* __restrict__ row_ptr,
                            const long long* __restrict__ csr,
                            const unsigned short* __restrict__ xin,
                            unsigned short* __restrict__ xout) {
    int tid = blockIdx.x * blockDim.x + threadIdx.x;
    int row = tid >> 5;
    if (row >= N_NODES) return;
    const int ll  = tid & 31;
    const int j   = ll >> 2;     // edge slot 0..7
    const int seg = ll & 3;      // 8-dim segment 0..3
    const int s = row_ptr[row];
    const int e = row_ptr[row + 1];

    float acc[8];
    #pragma unroll
    for (int k = 0; k < 8; ++k) acc[k] = 0.f;

    for (int i = s; i < e; i += 16) {
        int ea = i + j;
        int eb = i + 8 + j;
        long long pa = (ea < e) ? csr[ea] : 0LL;
        long long pb = (eb < e) ? csr[eb] : 0LL;
        const uint4* qa = (const uint4*)(xin + ((unsigned)pa) * DIM) + seg;
        const uint4* qb = (const uint4*)(xin + ((unsigned)pb) * DIM) + seg;
        uint4 va = *qa;
        uint4 vb = *qb;
        float wa = __int_as_float((int)(pa >> 32));
        float wb = __int_as_float((int)(pb >> 32));
        acc[0] += wa * bflo(va.x); acc[1] += wa * bfhi(va.x);
        acc[2] += wa * bflo(va.y); acc[3] += wa * bfhi(va.y);
        acc[4] += wa * bflo(va.z); acc[5] += wa * bfhi(va.z);
        acc[6] += wa * bflo(va.w); acc[7] += wa * bfhi(va.w);
        acc[0] += wb * bflo(vb.x); acc[1] += wb * bfhi(vb.x);
        acc[2] += wb * bflo(vb.y); acc[3] += wb * bfhi(vb.y);
        acc[4] += wb * bflo(vb.z); acc[5] += wb * bfhi(vb.z);
        acc[6] += wb * bflo(vb.w); acc[7] += wb * bfhi(vb.w);
    }

    #pragma unroll
    for (int m = 4; m <= 16; m <<= 1) {
        #pragma unroll
        for (int k = 0; k < 8; ++k) acc[k] += __shfl_xor(acc[k], m, 64);
    }

    if (j == 0) {
        int o = row * DIM + seg * 8;
        uint4 h;
        h.x = (unsigned)f2bf(acc[0]) | ((unsigned)f2bf(acc[1]) << 16);
        h.y = (unsigned)f2bf(acc[2]) | ((unsigned)f2bf(acc[3]) << 16);
        h.z = (unsigned)f2bf(acc[4]) | ((unsigned)f2bf(acc[5]) << 16);
        h.w = (unsigned)f2bf(acc[6]) | ((unsigned)f2bf(acc[7]) << 16);
        *(uint4*)(xout + o) = h;
    }
}

// ---------------------------------------------------------------------------
// Readout: light = (e + x1 + x2 + x3)/4 reconstructed per accessed node.
// ---------------------------------------------------------------------------
__device__ __forceinline__ void add_bf16_row(float* s, const unsigned short* x, size_t node) {
    const uint4* p = (const uint4*)(x + node * DIM);
    #pragma unroll
    for (int k = 0; k < 4; ++k) {
        uint4 t = p[k];
        s[k * 8 + 0] += bflo(t.x); s[k * 8 + 1] += bfhi(t.x);
        s[k * 8 + 2] += bflo(t.y); s[k * 8 + 3] += bfhi(t.y);
        s[k * 8 + 4] += bflo(t.z); s[k * 8 + 5] += bfhi(t.z);
        s[k * 8 + 6] += bflo(t.w); s[k * 8 + 7] += bfhi(t.w);
    }
}

__global__ void final_kernel(const int* __restrict__ users,
                             const int* __restrict__ items,
                             const float* __restrict__ user_emb,
                             const float* __restrict__ item_emb,
                             const unsigned short* __restrict__ x1,
                             const unsigned short* __restrict__ x2,
                             const unsigned short* __restrict__ x3,
                             const float* __restrict__ means,
                             const float* __restrict__ stds,
                             float* __restrict__ out) {
    int b = blockIdx.x * blockDim.x + threadIdx.x;
    if (b >= B_OUT) return;
    int u  = users[b];
    int itm = items[b];
    size_t un = (size_t)u;
    size_t in = (size_t)(N_USERS + itm);

    float su[DIM], si[DIM];
    const float4* eu = (const float4*)(user_emb + un * DIM);
    const float4* ei = (const float4*)(item_emb + (size_t)itm * DIM);
    #pragma unroll
    for (int k = 0; k < 8; ++k) {
        float4 a = eu[k];
        su[k * 4 + 0] = a.x; su[k * 4 + 1] = a.y; su[k * 4 + 2] = a.z; su[k * 4 + 3] = a.w;
        float4 c = ei[k];
        si[k * 4 + 0] = c.x; si[k * 4 + 1] = c.y; si[k * 4 + 2] = c.z; si[k * 4 + 3] = c.w;
    }
    add_bf16_row(su, x1, un); add_bf16_row(su, x2, un); add_bf16_row(su, x3, un);
    add_bf16_row(si, x1, in); add_bf16_row(si, x2, in); add_bf16_row(si, x3, in);

    float gamma = 0.f;
    #pragma unroll
    for (int d = 0; d < DIM; ++d) gamma += su[d] * si[d];
    gamma *= 0.0625f;   // (1/4)*(1/4)
    out[b] = gamma * stds[u] + means[u];
}

extern "C" void kernel_launch(void* const* d_in, const int* in_sizes, int n_in,
                              void* d_out, int out_size, void* d_ws, size_t ws_size,
                              hipStream_t stream) {
    const int*   users    = (const int*)d_in[0];
    const int*   items    = (const int*)d_in[1];
    const int*   rows     = (const int*)d_in[2];
    const int*   cols     = (const int*)d_in[3];
    const float* vals     = (const float*)d_in[4];
    const float* user_emb = (const float*)d_in[5];
    const float* item_emb = (const float*)d_in[6];
    const float* means    = (const float*)d_in[7];
    const float* stds     = (const float*)d_in[8];
    float* out = (float*)d_out;

    char* w = (char*)d_ws;
    size_t off = 0;
    auto alloc = [&](size_t bytes) -> void* {
        void* p = w + off;
        off = (off + bytes + 255) & ~(size_t)255;
        return p;
    };
    // Region A: bucket_ev (live: part -> mini_scatter) aliases
    //           {x_a, x_b, x_c, x_d} (live: init -> end).
    size_t regionA = ((size_t)N_PBLK * CH * sizeof(int2) + 255) & ~(size_t)255;  // 64.1 MB
    char* a0 = (char*)alloc(regionA);
    int2* bucket_ev = (int2*)a0;
    size_t aoff = 0;
    auto allocA = [&](size_t bytes) -> void* {
        void* p = a0 + aoff;
        aoff = (aoff + bytes + 255) & ~(size_t)255;
        return p;
    };
    unsigned short* x_a = (unsigned short*)allocA((size_t)N_NODES * DIM * 2);  // 9.6 MB
    unsigned short* x_b = (unsigned short*)allocA((size_t)N_NODES * DIM * 2);  // 9.6 MB
    unsigned short* x_c = (unsigned short*)allocA((size_t)N_NODES * DIM * 2);  // 9.6 MB
    unsigned short* x_d = (unsigned short*)allocA((size_t)N_NODES * DIM * 2);  // 9.6 MB (38.4 <= 64.1)

    int*  runstart = (int*) alloc((size_t)N_PBLK * RS_LD * sizeof(int));       // 2.0 MB
    int*  partial  = (int*) alloc((size_t)NRED * NB * sizeof(int));
    int*  row_ptr  = (int*) alloc((size_t)(N_NODES + 1) * sizeof(int));
    int*  bcsr     = (int*) alloc((size_t)NB * sizeof(int));
    int2* csr_ev   = (int2*)alloc((size_t)N_EDGES * sizeof(int2));              // 64 MB
    const long long* csr = (const long long*)csr_ev;
    (void)ws_size;

    const int g_init  = (N_NODES * DIM / 4 + T - 1) / T;
    const int g_spmm  = (N_NODES * DIM + T - 1) / T;     // 18750
    const int g_final = (B_OUT + T - 1) / T;

    // --- CSR build (panel-sorted within rows, fully LDS-staged writes) ---
    part_kernel<<<N_PBLK, PART_T, 0, stream>>>(rows, cols, vals, runstart, bucket_ev);
    btot_kernel<<<NRED, NB, 0, stream>>>(runstart, partial);
    bscan_kernel<<<1, NB, 0, stream>>>(partial, bcsr, row_ptr);
    mini_scatter_kernel<<<NB, MS_T, 0, stream>>>(runstart, bucket_ev, bcsr, row_ptr, csr_ev);

    // --- dense pipeline (bucket_ev dead from here; region reused) ---
    init_kernel<<<g_init, T, 0, stream>>>(user_emb, item_emb, x_a);
    spmm_kernel<<<g_spmm, T, 0, stream>>>(row_ptr, csr, x_a, x_b);
    spmm_kernel<<<g_spmm, T, 0, stream>>>(row_ptr, csr, x_b, x_c);
    spmm_kernel<<<g_spmm, T, 0, stream>>>(row_ptr, csr, x_c, x_d);

    final_kernel<<<g_final, T, 0, stream>>>(users, items, user_emb, item_emb,
                                            x_b, x_c, x_d, means, stds, out);
}